// Round 1
// baseline (211.036 us; speedup 1.0000x reference)
//
#include <hip/hip_runtime.h>
#include <hip/hip_bf16.h>

// Mex forward: B=64,C=64,H=W=64, BLK=(64,3,3), STR=(64,2,2), PAD=(0,1,1),
// NI=256, EPS=1, mean mode. OH=OW=32, K=576, out (64,256,32,32) fp32.
//
// y[n][i] = log( sum_k exp(P[n][k] + O[i][k]) ) - log(576)
// (shift-invariant: no max-subtraction needed; x ~ N(0,1), eps=1 -> exp in
//  [e-5.5, e+5.5], safe in bf16/fp32. Zero-padded patch entries -> exp(0)=1.)
//
// K reordered as k' = (fh*3+fw)*64 + c on BOTH operands so A-fragments are
// 8 consecutive channels -> read directly from a [h][w][c] exp(x) LDS image.

typedef __bf16 bf16x8 __attribute__((ext_vector_type(8)));
typedef float  f32x4  __attribute__((ext_vector_type(4)));

// ---- Bt[i][k'] = bf16(exp(offsets[i][c][fh][fw])), k' = p*64 + c ----------
__global__ void mex_prep_b(const float* __restrict__ off, __bf16* __restrict__ Bt) {
    const int i = blockIdx.x;        // instance 0..255
    const int c = threadIdx.x;       // 0..63
    const float* oi = off + i * 576;
    __bf16* bi = Bt + i * 576;
    #pragma unroll
    for (int p = 0; p < 9; ++p) {
        float v = oi[c * 9 + p];     // original k = c*9 + p
        bi[p * 64 + c] = (__bf16)__expf(v);
    }
}

// ---- main fused kernel ----------------------------------------------------
// block: 256 thr (4 waves). Handles one (b, oh-pair): 64 rows x 256 inst.
// wave w: all 64 rows x instances [w*64, w*64+64): 4 m-tiles x 4 n-tiles.
__global__ __launch_bounds__(256, 3) void mex_main(
        const float* __restrict__ x,
        const __bf16* __restrict__ Bt,
        float* __restrict__ out) {
    // exp(x) image: [h 0..4][w_idx 0..65][c 0..63] bf16, c-chunks-of-8
    // swizzled: chunk_pos = cc ^ ((row>>1)&7), row = h*66 + w_idx. 42240 B.
    __shared__ bf16x8 lds8[5 * 66 * 8];

    const int bid = blockIdx.x;      // 0..1023
    const int b   = bid >> 4;        // batch
    const int oh0 = (bid & 15) << 1; // first oh of the pair

    const int tid = threadIdx.x;

    // ---- stage exp(x) region (coalesced 256B row reads, b128 LDS writes) --
    {
        const int w  = tid & 63;
        const int qt = tid >> 6;
        if (tid < 40) {              // w_idx = 0 pad column (w = -1): exp(0)=1
            const int hl = tid >> 3, cc = tid & 7;
            const int row = hl * 66;
            const int chunk = cc ^ ((row >> 1) & 7);
            bf16x8 one;
            #pragma unroll
            for (int j = 0; j < 8; ++j) one[j] = (__bf16)1.0f;
            lds8[row * 8 + chunk] = one;
        }
        for (int hc = qt; hc < 40; hc += 4) {  // 5 h-rows x 8 c-chunks
            const int hl = hc >> 3;
            const int cc = hc & 7;
            const int hg = 2 * oh0 - 1 + hl;   // global h, may be -1
            const bool vh = (hg >= 0) && (hg < 64);  // wave-uniform
            const float* xp = x + (((b * 64 + cc * 8) * 64 + hg) * 64 + w);
            bf16x8 vals;
            #pragma unroll
            for (int j = 0; j < 8; ++j) {
                float v = vh ? xp[j * 4096] : 0.0f;  // OOB row -> x=0
                vals[j] = (__bf16)__expf(v);
            }
            const int row = hl * 66 + w + 1;
            const int chunk = cc ^ ((row >> 1) & 7);
            lds8[row * 8 + chunk] = vals;
        }
    }
    __syncthreads();   // the ONLY barrier — K-loop below is barrier-free

    const int t16 = tid & 15;
    const int q   = (tid >> 4) & 3;
    const int wv  = tid >> 6;

    // per-lane A row bases: m = mt*16 + t16 -> row = 132*(m>>5) + 2*(m&31)
    int rbase[4];
    #pragma unroll
    for (int mt = 0; mt < 4; ++mt) {
        const int m = mt * 16 + t16;
        rbase[mt] = ((m >> 5) * 132) + ((m & 31) * 2);
    }

    const bf16x8* __restrict__ Btv = (const bf16x8*)Bt;  // 72 chunks / inst
    const int instRow = (wv * 64 + t16) * 72 + q;        // + ks*4 per step

    f32x4 acc[4][4];
    #pragma unroll
    for (int mt = 0; mt < 4; ++mt)
        #pragma unroll
        for (int nt = 0; nt < 4; ++nt)
            acc[mt][nt] = (f32x4)(0.0f);

    bf16x8 bcur[4];
    #pragma unroll
    for (int nt = 0; nt < 4; ++nt)
        bcur[nt] = Btv[instRow + nt * (16 * 72)];

    #pragma unroll 2
    for (int ks = 0; ks < 18; ++ks) {
        const int p  = ks >> 1;            // patch position 0..8
        const int fh = (p * 11) >> 5;      // p/3
        const int fw = p - fh * 3;
        const int rofs = fh * 66 + fw;
        const int ccq  = ((ks & 1) << 2) + q;   // c-chunk this lane reads

        bf16x8 a[4];
        #pragma unroll
        for (int mt = 0; mt < 4; ++mt) {
            const int row = rbase[mt] + rofs;       // h*66 + 2*ow + fw
            const int chunk = ccq ^ ((row >> 1) & 7);
            a[mt] = lds8[row * 8 + chunk];          // ds_read_b128
        }

        bf16x8 bnext[4];
        if (ks < 17) {                      // prefetch next K-step's B frags
            #pragma unroll
            for (int nt = 0; nt < 4; ++nt)
                bnext[nt] = Btv[instRow + nt * (16 * 72) + (ks + 1) * 4];
        }

        #pragma unroll
        for (int mt = 0; mt < 4; ++mt)
            #pragma unroll
            for (int nt = 0; nt < 4; ++nt)
                acc[mt][nt] = __builtin_amdgcn_mfma_f32_16x16x32_bf16(
                    a[mt], bcur[nt], acc[mt][nt], 0, 0, 0);

        #pragma unroll
        for (int nt = 0; nt < 4; ++nt) bcur[nt] = bnext[nt];
    }

    // ---- epilogue: y = log(S) - log(576); out[b][inst][oh][ow] ------------
    const float lK = 6.356107660695891f;   // log(576)
    #pragma unroll
    for (int mt = 0; mt < 4; ++mt) {
        const int m   = mt * 16 + (q << 2);   // C/D: row = q*4 + reg
        const int ohl = m >> 5;
        const int owi = m & 31;
        const int orow = (oh0 + ohl) * 32 + owi;
        #pragma unroll
        for (int nt = 0; nt < 4; ++nt) {
            const int inst = wv * 64 + nt * 16 + t16;  // C/D: col = lane&15
            f32x4 r;
            #pragma unroll
            for (int j = 0; j < 4; ++j)
                r[j] = __logf(acc[mt][nt][j]) - lK;
            *(f32x4*)(out + ((b * 256 + inst) * 1024 + orow)) = r;
        }
    }
}

extern "C" void kernel_launch(void* const* d_in, const int* in_sizes, int n_in,
                              void* d_out, int out_size, void* d_ws, size_t ws_size,
                              hipStream_t stream) {
    const float* x   = (const float*)d_in[0];   // (64,64,64,64) fp32
    const float* off = (const float*)d_in[1];   // (1,256,64,3,3) fp32
    float* out = (float*)d_out;                 // (64,256,32,32) fp32
    __bf16* Bt = (__bf16*)d_ws;                 // 256*576*2 = 294912 B scratch

    mex_prep_b<<<256, 64, 0, stream>>>(off, Bt);
    mex_main<<<1024, 256, 0, stream>>>(x, Bt, out);
}

// Round 2
// 157.051 us; speedup vs baseline: 1.3437x; 1.3437x over previous
//
#include <hip/hip_runtime.h>
#include <hip/hip_bf16.h>

// Mex forward: B=64,C=64,H=W=64, BLK=(64,3,3), STR=(64,2,2), PAD=(0,1,1),
// NI=256, EPS=1, mean mode. OH=OW=32, K=576, out (64,256,32,32) fp32.
//
// y[n][i] = log( sum_k exp(P[n][k] + O[i][k]) ) - log(576)
// Shift-invariant -> no max pass. Zero-padded entries -> exp(0)=1.
//
// Pipeline:
//   1) mex_prep_b : Bt[i][k'] = bf16(exp(off)), k' = (fh*3+fw)*64 + c
//   2) mex_exp_tr : E[b][h][w][c] = bf16(exp(x)), c-chunks-of-8 stored at
//                   position c8 ^ ((w>>1)&7)  (bank swizzle pre-baked so the
//                   async DMA staging in 3) lands swizzled in LDS)
//   3) mex_main   : per (b, oh-pair): global_load_lds dwordx4 stages 5 rows
//                   of E into LDS, barrier, 18-step barrier-free MFMA K-loop.

typedef __bf16 bf16x8 __attribute__((ext_vector_type(8)));
typedef float  f32x4  __attribute__((ext_vector_type(4)));

#define GLD16(gp, lp) __builtin_amdgcn_global_load_lds(                        \
    (const __attribute__((address_space(1))) unsigned int*)(gp),               \
    (__attribute__((address_space(3))) unsigned int*)(lp), 16, 0, 0)

// ---- Bt[i][k'] = bf16(exp(offsets[i][c][fh][fw])), k' = p*64 + c ----------
__global__ void mex_prep_b(const float* __restrict__ off, __bf16* __restrict__ Bt) {
    const int i = blockIdx.x * 4 + (threadIdx.x >> 6);  // instance
    const int c = threadIdx.x & 63;
    const float* oi = off + i * 576;
    __bf16* bi = Bt + i * 576;
    #pragma unroll
    for (int p = 0; p < 9; ++p) {
        float v = oi[c * 9 + p];     // original k = c*9 + p
        bi[p * 64 + c] = (__bf16)__expf(v);
    }
}

// ---- E[b][h][w][c8-swizzled] = bf16(exp(x[b][c][h][w])) -------------------
__global__ __launch_bounds__(256) void mex_exp_tr(const float* __restrict__ x,
                                                  __bf16* __restrict__ E) {
    __shared__ __bf16 t[64 * 68];    // [c][w], stride 68 (8B-aligned rows)
    const int bh = blockIdx.x;       // b*64 + h
    const int b  = bh >> 6, h = bh & 63;
    const float* xp = x + ((size_t)b << 18) + (h << 6);   // + c*4096 + w
    const int tid = threadIdx.x;

    #pragma unroll
    for (int i = 0; i < 4; ++i) {    // 1024 float4 / 256 thr
        const int f  = tid + i * 256;
        const int c  = f >> 4;
        const int w0 = (f & 15) << 2;
        float4 v = *(const float4*)(xp + c * 4096 + w0);
        __bf16* d = &t[c * 68 + w0];
        d[0] = (__bf16)__expf(v.x);
        d[1] = (__bf16)__expf(v.y);
        d[2] = (__bf16)__expf(v.z);
        d[3] = (__bf16)__expf(v.w);
    }
    __syncthreads();

    __bf16* Erow = E + ((size_t)bh << 12);   // 4096 bf16 per (b,h) row
    #pragma unroll
    for (int j = 0; j < 2; ++j) {    // 512 chunks / 256 thr
        const int id = tid + j * 256;
        const int w = id >> 3, c8 = id & 7;
        bf16x8 v;
        #pragma unroll
        for (int ii = 0; ii < 8; ++ii) v[ii] = t[(c8 * 8 + ii) * 68 + w];
        const int c8p = c8 ^ ((w >> 1) & 7);       // baked swizzle
        *(bf16x8*)(Erow + w * 64 + c8p * 8) = v;   // contiguous 128B per 8 lanes
    }
}

// ---- main fused kernel ----------------------------------------------------
__global__ __launch_bounds__(256, 3) void mex_main(
        const __bf16* __restrict__ E,
        const __bf16* __restrict__ Bt,
        float* __restrict__ out) {
    // [hl 0..4][w_idx 0..65][chunk 0..7] bf16x8; w_idx = w_global+1. 42240 B.
    __shared__ bf16x8 lds8[5 * 66 * 8];

    const int bid = blockIdx.x;      // 0..1023
    const int b   = bid >> 4;
    const int oh0 = (bid & 15) << 1;
    const int tid  = threadIdx.x;
    const int lane = tid & 63;
    const int wv   = tid >> 6;

    // ---- pad fills (LDS stores) ------------------------------------------
    bf16x8 one8;
    #pragma unroll
    for (int j = 0; j < 8; ++j) one8[j] = (__bf16)1.0f;
    if (tid < 40) {                  // w_idx = 0 column (w_global = -1)
        const int hl = tid >> 3, cc = tid & 7;
        lds8[(hl * 66) * 8 + cc] = one8;
    }
    if (oh0 == 0) {                  // h_global = -1 -> whole hl=0 row = ones
        for (int i = tid; i < 66 * 8; i += 256) lds8[i] = one8;
    }

    // ---- async DMA: 40 segments of 1 KB, 10 per wave ---------------------
    #pragma unroll
    for (int s = 0; s < 10; ++s) {
        const int seg = wv * 10 + s;
        const int hl = seg >> 3, sg = seg & 7;
        const int hg = 2 * oh0 - 1 + hl;           // -1..63
        if (hg >= 0) {                             // wave-uniform predicate
            const __bf16* gp = E + (((size_t)b * 64 + hg) << 12) + (sg << 9) + (lane << 3);
            bf16x8* lp = lds8 + hl * 528 + 8 + sg * 64;   // uniform base
            GLD16(gp, lp);
        }
    }
    __syncthreads();   // drains vmcnt (DMA) + lgkm (pad writes); only barrier

    const int t16 = tid & 15;
    const int q   = (tid >> 4) & 3;

    int rbase[4], owv[4];
    #pragma unroll
    for (int mt = 0; mt < 4; ++mt) {
        const int m = mt * 16 + t16;
        owv[mt]   = m & 31;
        rbase[mt] = ((m >> 5) * 132) + ((m & 31) * 2);  // hl*66 + 2*ow part
    }

    const bf16x8* __restrict__ Btv = (const bf16x8*)Bt;  // 72 chunks / inst
    const int instRow = (wv * 64 + t16) * 72 + q;

    f32x4 acc[4][4];
    #pragma unroll
    for (int mt = 0; mt < 4; ++mt)
        #pragma unroll
        for (int nt = 0; nt < 4; ++nt)
            acc[mt][nt] = (f32x4)(0.0f);

    bf16x8 bcur[4];
    #pragma unroll
    for (int nt = 0; nt < 4; ++nt)
        bcur[nt] = Btv[instRow + nt * (16 * 72)];

    #pragma unroll 2
    for (int ks = 0; ks < 18; ++ks) {
        const int p  = ks >> 1;
        const int fh = (p * 11) >> 5;              // p/3
        const int fw = p - fh * 3;
        const int rofs = fh * 66 + fw;
        const int ccq  = ((ks & 1) << 2) + q;

        bf16x8 a[4];
        #pragma unroll
        for (int mt = 0; mt < 4; ++mt) {
            const int row = rbase[mt] + rofs;      // hl*66 + w_idx
            const int key = ((owv[mt] * 2 + fw - 1) >> 1) & 7;  // w-only swizzle
            a[mt] = lds8[row * 8 + (ccq ^ key)];
        }

        bf16x8 bnext[4];
        if (ks < 17) {
            #pragma unroll
            for (int nt = 0; nt < 4; ++nt)
                bnext[nt] = Btv[instRow + nt * (16 * 72) + (ks + 1) * 4];
        }

        #pragma unroll
        for (int mt = 0; mt < 4; ++mt)
            #pragma unroll
            for (int nt = 0; nt < 4; ++nt)
                acc[mt][nt] = __builtin_amdgcn_mfma_f32_16x16x32_bf16(
                    a[mt], bcur[nt], acc[mt][nt], 0, 0, 0);

        #pragma unroll
        for (int nt = 0; nt < 4; ++nt) bcur[nt] = bnext[nt];
    }

    // ---- epilogue: y = log(S) - log(576) ---------------------------------
    const float lK = 6.356107660695891f;   // log(576)
    #pragma unroll
    for (int mt = 0; mt < 4; ++mt) {
        const int m   = mt * 16 + (q << 2);        // C/D: row = q*4 + reg
        const int ohl = m >> 5;
        const int owi = m & 31;
        const int orow = (oh0 + ohl) * 32 + owi;
        #pragma unroll
        for (int nt = 0; nt < 4; ++nt) {
            const int inst = wv * 64 + nt * 16 + t16;   // C/D: col = lane&15
            f32x4 r;
            #pragma unroll
            for (int j = 0; j < 4; ++j)
                r[j] = __logf(acc[mt][nt][j]) - lK;
            *(f32x4*)(out + (((size_t)b * 256 + inst) * 1024 + orow)) = r;
        }
    }
}

extern "C" void kernel_launch(void* const* d_in, const int* in_sizes, int n_in,
                              void* d_out, int out_size, void* d_ws, size_t ws_size,
                              hipStream_t stream) {
    const float* x   = (const float*)d_in[0];   // (64,64,64,64) fp32
    const float* off = (const float*)d_in[1];   // (1,256,64,3,3) fp32
    float* out = (float*)d_out;                 // (64,256,32,32) fp32
    __bf16* E  = (__bf16*)d_ws;                 // 64*64*64*64*2 = 33554432 B
    __bf16* Bt = (__bf16*)((char*)d_ws + 33554432);   // 294912 B

    mex_prep_b<<<64, 256, 0, stream>>>(off, Bt);
    mex_exp_tr<<<4096, 256, 0, stream>>>(x, E);
    mex_main<<<1024, 256, 0, stream>>>(E, Bt, out);
}